// Round 7
// baseline (815.666 us; speedup 1.0000x reference)
//
#include <hip/hip_runtime.h>
#include <hip/hip_bf16.h>

// ShareDeLayer: 2x cross-attention + 2x LayerNorm + top2-of-8 MoE FFN.
// Q=1024, S=1024, B=8, D=256, H=8, hd=32, FF=1024, E=8, K=2.
// Pre-gate chain: bf16x2-split MFMA (3 products) ~= fp32 fidelity so the
// discrete top-2 routing matches the numpy fp32 reference.
// Round 7: attention — swapped QK^T (mfma(K,Q)) makes the score C-layout
// coincide with the K=16 MFMA A-fragment layout, so P feeds PV directly in
// registers: NO LDS, NO barriers, NO cross-lane ops in the loop. Compiler
// free to pipeline K/V loads across iterations.

#define DEV static __device__ __forceinline__

typedef __hip_bfloat16 bf16;
typedef __bf16 b8 __attribute__((ext_vector_type(8)));
typedef __bf16 b4 __attribute__((ext_vector_type(4)));
typedef short s4 __attribute__((ext_vector_type(4)));
typedef float fx4 __attribute__((ext_vector_type(4)));

DEV bf16 f2b(float f) { return __float2bfloat16(f); }
DEV float b2f(bf16 h) { return __bfloat162float(h); }

DEV fx4 mfma16(b4 a, b4 b, fx4 c) {
#if __has_builtin(__builtin_amdgcn_mfma_f32_16x16x16_bf16)
  return __builtin_amdgcn_mfma_f32_16x16x16_bf16(a, b, c, 0, 0, 0);
#elif __has_builtin(__builtin_amdgcn_mfma_f32_16x16x16bf16_1k)
  s4 as = __builtin_bit_cast(s4, a);
  s4 bs = __builtin_bit_cast(s4, b);
  return __builtin_amdgcn_mfma_f32_16x16x16bf16_1k(as, bs, c, 0, 0, 0);
#else
  asm("v_mfma_f32_16x16x16_bf16 %0, %1, %2, %0" : "+v"(c) : "v"(a), "v"(b));
  return c;
#endif
}

// ---------------- single-precision MFMA core (MoE experts) -----------------
template <int KSTEPS>
DEV void gemm_core(const bf16* __restrict__ A, const int* arow, int lda,
                   const bf16* __restrict__ W, int nbase, int ldb, int lane,
                   fx4 acc[4][4]) {
  const int r = lane & 15, ko = (lane >> 4) * 8;
  const b8* ap[4];
  const b8* bp[4];
#pragma unroll
  for (int i = 0; i < 4; ++i) {
    ap[i] = reinterpret_cast<const b8*>(A + (size_t)arow[i] * lda + ko);
    bp[i] = reinterpret_cast<const b8*>(W + (size_t)(nbase + i * 16 + r) * ldb + ko);
  }
#pragma unroll 4
  for (int ks = 0; ks < KSTEPS; ++ks) {
    b8 a[4], b[4];
#pragma unroll
    for (int i = 0; i < 4; ++i) { a[i] = ap[i][ks * 4]; b[i] = bp[i][ks * 4]; }
#pragma unroll
    for (int i = 0; i < 4; ++i)
#pragma unroll
      for (int j = 0; j < 4; ++j)
        acc[i][j] = __builtin_amdgcn_mfma_f32_16x16x32_bf16(a[i], b[j], acc[i][j], 0, 0, 0);
  }
}

// ---------------- split (hi+lo) MFMA core: ~fp32 via 3 products ------------
template <int KSTEPS>
DEV void gemm3(const bf16* __restrict__ Ah, const bf16* __restrict__ Al,
               const int* arow, int lda,
               const bf16* __restrict__ Wh, const bf16* __restrict__ Wl,
               int nbase, int ldb, int lane, fx4 acc[4][4]) {
  const int r = lane & 15, ko = (lane >> 4) * 8;
  const b8 *aph[4], *apl[4], *bph[4], *bpl[4];
#pragma unroll
  for (int i = 0; i < 4; ++i) {
    size_t ao = (size_t)arow[i] * lda + ko;
    size_t bo = (size_t)(nbase + i * 16 + r) * ldb + ko;
    aph[i] = reinterpret_cast<const b8*>(Ah + ao);
    apl[i] = reinterpret_cast<const b8*>(Al + ao);
    bph[i] = reinterpret_cast<const b8*>(Wh + bo);
    bpl[i] = reinterpret_cast<const b8*>(Wl + bo);
  }
#pragma unroll 2
  for (int ks = 0; ks < KSTEPS; ++ks) {
    b8 ah[4], al[4], bh[4], bl[4];
#pragma unroll
    for (int i = 0; i < 4; ++i) {
      ah[i] = aph[i][ks * 4]; al[i] = apl[i][ks * 4];
      bh[i] = bph[i][ks * 4]; bl[i] = bpl[i][ks * 4];
    }
#pragma unroll
    for (int i = 0; i < 4; ++i)
#pragma unroll
      for (int j = 0; j < 4; ++j) {
        acc[i][j] = __builtin_amdgcn_mfma_f32_16x16x32_bf16(ah[i], bh[j], acc[i][j], 0, 0, 0);
        acc[i][j] = __builtin_amdgcn_mfma_f32_16x16x32_bf16(ah[i], bl[j], acc[i][j], 0, 0, 0);
        acc[i][j] = __builtin_amdgcn_mfma_f32_16x16x32_bf16(al[i], bh[j], acc[i][j], 0, 0, 0);
      }
  }
}

// ---------------- fp32 -> bf16 hi/lo split converter -----------------------
struct CvtS {
  const float* s[7];
  bf16* dh[7];
  bf16* dl[7];
  int cum[8];
};

__global__ __launch_bounds__(256) void k_cvt_split(CvtS c, int total4) {
  int i = blockIdx.x * 256 + threadIdx.x;
  if (i >= total4) return;
  int idx = i * 4;
#pragma unroll
  for (int seg = 0; seg < 7; ++seg) {
    if (idx < c.cum[seg + 1]) {
      int l = idx - c.cum[seg];
      float4 v = *reinterpret_cast<const float4*>(c.s[seg] + l);
      bf16* dh = c.dh[seg] + l;
      bf16* dl = c.dl[seg] + l;
      float a[4] = {v.x, v.y, v.z, v.w};
#pragma unroll
      for (int t = 0; t < 4; ++t) {
        bf16 h = f2b(a[t]);
        dh[t] = h;
        dl[t] = f2b(a[t] - b2f(h));
      }
      return;
    }
  }
}

struct CvtP {
  const float* s[2];
  bf16* d[2];
  int cum[3];
};

__global__ __launch_bounds__(256) void k_cvt(CvtP c, int total4) {
  int i = blockIdx.x * 256 + threadIdx.x;
  if (i >= total4) return;
  int idx = i * 4;
#pragma unroll
  for (int seg = 0; seg < 2; ++seg) {
    if (idx < c.cum[seg + 1]) {
      int l = idx - c.cum[seg];
      float4 v = *reinterpret_cast<const float4*>(c.s[seg] + l);
      bf16* dp = c.d[seg] + l;
      dp[0] = f2b(v.x); dp[1] = f2b(v.y); dp[2] = f2b(v.z); dp[3] = f2b(v.w);
      return;
    }
  }
}

// ---------------- Q projection (split, fused 1/sqrt(32)) -------------------
__global__ __launch_bounds__(256) void k_qproj_s(
    const bf16* __restrict__ Ah, const bf16* __restrict__ Al,
    const bf16* __restrict__ Wh, const bf16* __restrict__ Wl,
    const float* __restrict__ bias,
    bf16* __restrict__ qh, bf16* __restrict__ ql, int isCA) {
  const int w = threadIdx.x >> 6, lane = threadIdx.x & 63;
  const int mbase = blockIdx.x * 128 + (w >> 1) * 64;
  const int nbase = blockIdx.y * 128 + (w & 1) * 64;
  const int r = lane & 15, g4 = lane >> 4;
  int arow[4];
#pragma unroll
  for (int i = 0; i < 4; ++i) arow[i] = mbase + i * 16 + r;
  fx4 acc[4][4] = {};
  gemm3<8>(Ah, Al, arow, 256, Wh, Wl, nbase, 256, lane, acc);
#pragma unroll
  for (int i = 0; i < 4; ++i)
#pragma unroll
    for (int j = 0; j < 4; ++j)
#pragma unroll
      for (int jj = 0; jj < 4; ++jj) {
        int mm = mbase + i * 16 + g4 * 4 + jj;
        int nn = nbase + j * 16 + r;
        float v = (acc[i][j][jj] + bias[nn]) * 0.17677669529663687f;
        int h = nn >> 5, d = nn & 31;
        size_t o;
        if (isCA) o = (((size_t)((mm & 7) * 8 + h)) * 1024 + (mm >> 3)) * 32 + d;
        else      o = ((size_t)h * 1024 + mm) * 32 + d;
        bf16 hv = f2b(v);
        qh[o] = hv;
        ql[o] = f2b(v - b2f(hv));
      }
}

// ---------------- K/V projection (split; N=512 [wk;wv]) --------------------
__global__ __launch_bounds__(256) void k_kvproj_s(
    const bf16* __restrict__ Ah, const bf16* __restrict__ Al,
    const bf16* __restrict__ Wh, const bf16* __restrict__ Wl,
    const float* __restrict__ bias,
    bf16* __restrict__ kh, bf16* __restrict__ kl,
    bf16* __restrict__ vh, bf16* __restrict__ vl) {
  const int w = threadIdx.x >> 6, lane = threadIdx.x & 63;
  const int mbase = blockIdx.x * 128 + (w >> 1) * 64;
  const int nbase = blockIdx.y * 128 + (w & 1) * 64;
  const int r = lane & 15, g4 = lane >> 4;
  int arow[4];
#pragma unroll
  for (int i = 0; i < 4; ++i) arow[i] = mbase + i * 16 + r;
  fx4 acc[4][4] = {};
  gemm3<8>(Ah, Al, arow, 256, Wh, Wl, nbase, 256, lane, acc);
#pragma unroll
  for (int i = 0; i < 4; ++i)
#pragma unroll
    for (int j = 0; j < 4; ++j)
#pragma unroll
      for (int jj = 0; jj < 4; ++jj) {
        int mm = mbase + i * 16 + g4 * 4 + jj;
        int nn = nbase + j * 16 + r;
        float v = acc[i][j][jj] + bias[nn];
        int s = mm >> 3, bb = mm & 7;
        int hh = (nn & 255) >> 5, d = nn & 31;
        bf16 hv = f2b(v);
        bf16 lv = f2b(v - b2f(hv));
        if (nn < 256) {
          size_t o = (((size_t)(bb * 8 + hh)) * 1024 + s) * 32 + d;
          kh[o] = hv; kl[o] = lv;
        } else {
          size_t o = (((size_t)(bb * 8 + hh)) * 32 + d) * 1024 + s;
          vh[o] = hv; vl[o] = lv;
        }
      }
}

// ---------------- flash attention, split precision, register-only loop -----
// grid (32, 64); flat id n = c + 8*(xt + 32*a) pins bh = 8a+c to XCD c.
// Block: 32 q rows; 4 waves = 2 q-tiles x 2 s-halves. Swapped QK^T:
// mfma(K,Q) -> C col = q (lane&15), row = s_local (4*g4+j). That equals the
// K=16 MFMA A-fragment layout, so exp(P) feeds PV directly in registers.
// Unnormalized softmax (max=0; scores O(1)); per-lane partial sums.
__global__ __launch_bounds__(256, 4) void k_attn_s(
    const bf16* __restrict__ qth, const bf16* __restrict__ qtl,
    const bf16* __restrict__ kth, const bf16* __restrict__ ktl,
    const bf16* __restrict__ vth, const bf16* __restrict__ vtl,
    bf16* __restrict__ aoh, bf16* __restrict__ aol, int caFlag) {
  __shared__ float Cb[4][64][12];
  const int w = threadIdx.x >> 6, lane = threadIdx.x & 63;
  const int n = blockIdx.y * 32 + blockIdx.x;
  const int cx = n & 7, rem = n >> 3;
  const int xt = rem & 31, a = rem >> 5;
  const int bh = a * 8 + cx;
  const int b = bh >> 3, h = bh & 7;
  const int q0 = xt * 32 + (w >> 1) * 16;
  const int sbase = (w & 1) * 512;
  const int r = lane & 15, g4 = lane >> 4, ko = g4 * 8;
  const size_t qoff = (size_t)(caFlag ? bh : h) * 32768;
  const size_t koff = (size_t)bh * 32768;
  const size_t voff = (size_t)bh * 32768;
  const b8 qfh = *reinterpret_cast<const b8*>(qth + qoff + (size_t)(q0 + r) * 32 + ko);
  const b8 qfl = *reinterpret_cast<const b8*>(qtl + qoff + (size_t)(q0 + r) * 32 + ko);
  fx4 o0 = {}, o1 = {};
  const fx4 zz = {};
  float lsum = 0.f;
  for (int it = 0; it < 8; ++it) {
    const int s0 = sbase + it * 64;
#pragma unroll
    for (int kb4 = 0; kb4 < 4; ++kb4) {
      const int st = s0 + kb4 * 16;
      size_t o = koff + (size_t)(st + r) * 32 + ko;
      b8 kfh = *reinterpret_cast<const b8*>(kth + o);
      b8 kfl = *reinterpret_cast<const b8*>(ktl + o);
      // scores^T: C[s_local][q] with col=q=lane&15, row=4*g4+j
      fx4 t = __builtin_amdgcn_mfma_f32_16x16x32_bf16(kfh, qfl, zz, 0, 0, 0);
      t = __builtin_amdgcn_mfma_f32_16x16x32_bf16(kfl, qfh, t, 0, 0, 0);
      fx4 sf = __builtin_amdgcn_mfma_f32_16x16x32_bf16(kfh, qfh, t, 0, 0, 0);
      b4 ph, pl;
#pragma unroll
      for (int j = 0; j < 4; ++j) {
        float p = __expf(sf[j]);
        lsum += p;
        __bf16 hv = (__bf16)p;
        ph[j] = hv;
        pl[j] = (__bf16)(p - (float)hv);
      }
      // PV: P fragment (A, K=16: row q=lane&15, k=4*g4+j) x V^T (B: row d,
      // k = s). O C-layout: col=d, row=q_local.
      const bf16* vb = vth + voff + (size_t)st + g4 * 4;
      const bf16* vbl = vtl + voff + (size_t)st + g4 * 4;
#pragma unroll
      for (int db = 0; db < 2; ++db) {
        size_t vo = (size_t)(db * 16 + r) * 1024;
        b4 v_h = *reinterpret_cast<const b4*>(vb + vo);
        b4 v_l = *reinterpret_cast<const b4*>(vbl + vo);
        fx4& oo = db ? o1 : o0;
        oo = mfma16(ph, v_h, oo);
        oo = mfma16(ph, v_l, oo);
        oo = mfma16(pl, v_h, oo);
      }
    }
  }
  // full row-sum for q=lane&15 over this s-half (sum the 4 g-groups)
  lsum += __shfl_xor(lsum, 16);
  lsum += __shfl_xor(lsum, 32);
  // ---- s-half combine ----
  __syncthreads();
  {
    float* cw = &Cb[w][lane][0];
    cw[0] = lsum;
#pragma unroll
    for (int j = 0; j < 4; ++j) { cw[1 + j] = o0[j]; cw[5 + j] = o1[j]; }
  }
  __syncthreads();
  if ((w & 1) == 0) {
    const float* cp = &Cb[w ^ 1][lane][0];
    float lt = lsum + cp[0];
#pragma unroll
    for (int j = 0; j < 4; ++j) {
      float lrow = __shfl(lt, 4 * g4 + j);  // lane whose q-col == this row
      float inv = 1.f / lrow;
      float a0 = (o0[j] + cp[1 + j]) * inv;
      float a1 = (o1[j] + cp[5 + j]) * inv;
      int q = q0 + 4 * g4 + j;
      size_t rowoff = ((size_t)q * 8 + b) * 256 + h * 32;
      bf16 h0 = f2b(a0), h1 = f2b(a1);
      aoh[rowoff + r] = h0;      aol[rowoff + r] = f2b(a0 - b2f(h0));
      aoh[rowoff + 16 + r] = h1; aol[rowoff + 16 + r] = f2b(a1 - b2f(h1));
    }
  }
}

// ---------------- out-proj (split) + bias + residual (fp32 out) ------------
__global__ __launch_bounds__(256) void k_oproj_s(
    const bf16* __restrict__ Ah, const bf16* __restrict__ Al,
    const bf16* __restrict__ Wh, const bf16* __restrict__ Wl,
    const float* __restrict__ bias, const float* __restrict__ res,
    int resBroadcast, float* __restrict__ yo) {
  const int w = threadIdx.x >> 6, lane = threadIdx.x & 63;
  const int mbase = blockIdx.x * 128 + (w >> 1) * 64;
  const int nbase = blockIdx.y * 128 + (w & 1) * 64;
  const int r = lane & 15, g4 = lane >> 4;
  int arow[4];
#pragma unroll
  for (int i = 0; i < 4; ++i) arow[i] = mbase + i * 16 + r;
  fx4 acc[4][4] = {};
  gemm3<8>(Ah, Al, arow, 256, Wh, Wl, nbase, 256, lane, acc);
#pragma unroll
  for (int i = 0; i < 4; ++i)
#pragma unroll
    for (int j = 0; j < 4; ++j)
#pragma unroll
      for (int jj = 0; jj < 4; ++jj) {
        int mm = mbase + i * 16 + g4 * 4 + jj;
        int nn = nbase + j * 16 + r;
        size_t roff = resBroadcast ? (size_t)(mm >> 3) * 256 : (size_t)mm * 256;
        yo[(size_t)mm * 256 + nn] = acc[i][j][jj] + bias[nn] + res[roff + nn];
      }
}

// ---------------- LayerNorm D=256; emits fp32 + bf16 hi/lo -----------------
__global__ __launch_bounds__(256) void k_ln(const float* __restrict__ y,
                                            const float* __restrict__ g,
                                            const float* __restrict__ bta,
                                            float* __restrict__ of,
                                            bf16* __restrict__ obh,
                                            bf16* __restrict__ obl) {
  const int row = blockIdx.x * 4 + (threadIdx.x >> 6);
  const int lane = threadIdx.x & 63;
  float4 x = reinterpret_cast<const float4*>(y + (size_t)row * 256)[lane];
  float s1 = x.x + x.y + x.z + x.w;
  float s2 = x.x * x.x + x.y * x.y + x.z * x.z + x.w * x.w;
#pragma unroll
  for (int m = 1; m < 64; m <<= 1) {
    s1 += __shfl_xor(s1, m);
    s2 += __shfl_xor(s2, m);
  }
  float mean = s1 * (1.0f / 256.0f);
  float var = s2 * (1.0f / 256.0f) - mean * mean;
  float rs = 1.0f / sqrtf(var + 1e-5f);
  float4 gv = reinterpret_cast<const float4*>(g)[lane];
  float4 bv = reinterpret_cast<const float4*>(bta)[lane];
  float o[4];
  o[0] = (x.x - mean) * rs * gv.x + bv.x;
  o[1] = (x.y - mean) * rs * gv.y + bv.y;
  o[2] = (x.z - mean) * rs * gv.z + bv.z;
  o[3] = (x.w - mean) * rs * gv.w + bv.w;
  float4 ov = {o[0], o[1], o[2], o[3]};
  reinterpret_cast<float4*>(of + (size_t)row * 256)[lane] = ov;
  bf16* dh = obh + (size_t)row * 256 + lane * 4;
  bf16* dl = obl + (size_t)row * 256 + lane * 4;
#pragma unroll
  for (int t = 0; t < 4; ++t) {
    bf16 hv = f2b(o[t]);
    dh[t] = hv;
    dl[t] = f2b(o[t] - b2f(hv));
  }
}

// ---------------- MoE gate: top2-of-8 (fp64 acc), NO atomics ---------------
__global__ __launch_bounds__(256) void k_gate(const float* __restrict__ x,
                                              const float* __restrict__ gw,
                                              const float* __restrict__ gb,
                                              int* __restrict__ e0a, int* __restrict__ e1a,
                                              float* __restrict__ w0a, float* __restrict__ w1a) {
  __shared__ float W[2048];
  const int tid = threadIdx.x;
  for (int i = tid; i < 2048; i += 256) W[i] = gw[i];
  __syncthreads();
  const int wv = tid >> 6, lane = tid & 63;
  const int t = blockIdx.x * 4 + wv;
  float4 v = reinterpret_cast<const float4*>(x + (size_t)t * 256)[lane];
  double pe[8];
#pragma unroll
  for (int e = 0; e < 8; ++e) {
    float4 wv4 = reinterpret_cast<const float4*>(&W[e * 256])[lane];
    pe[e] = (double)v.x * wv4.x + (double)v.y * wv4.y +
            (double)v.z * wv4.z + (double)v.w * wv4.w;
  }
#pragma unroll
  for (int e = 0; e < 8; ++e)
#pragma unroll
    for (int m = 1; m < 64; m <<= 1) pe[e] += __shfl_xor(pe[e], m);
  if (lane == 0) {
    float lg[8];
#pragma unroll
    for (int e = 0; e < 8; ++e) lg[e] = (float)(pe[e] + (double)gb[e]);
    int e0 = 0; float v0 = lg[0];
#pragma unroll
    for (int e = 1; e < 8; ++e) if (lg[e] > v0) { v0 = lg[e]; e0 = e; }
    int e1 = -1; float v1 = -1e30f;
#pragma unroll
    for (int e = 0; e < 8; ++e) {
      if (e == e0) continue;
      if (lg[e] > v1) { v1 = lg[e]; e1 = e; }
    }
    float z = __expf(v1 - v0);
    float inv = 1.f / (1.f + z);
    e0a[t] = e0; e1a[t] = e1; w0a[t] = inv; w1a[t] = z * inv;
  }
}

// ---------------- ballot histogram: part[chunk][8], chunk = 256 tokens -----
__global__ __launch_bounds__(256) void k_hist(const int* __restrict__ e0a,
                                              const int* __restrict__ e1a,
                                              int* __restrict__ part) {
  __shared__ int lh[4][8];
  const int tid = threadIdx.x, w = tid >> 6;
  const int t = blockIdx.x * 256 + tid;
  const int e0 = e0a[t], e1 = e1a[t];
  int cnt[8];
#pragma unroll
  for (int e = 0; e < 8; ++e) {
    unsigned long long m0 = __ballot(e0 == e);
    unsigned long long m1 = __ballot(e1 == e);
    cnt[e] = __popcll(m0) + __popcll(m1);
  }
  if ((tid & 63) == 0) {
#pragma unroll
    for (int e = 0; e < 8; ++e) lh[w][e] = cnt[e];
  }
  __syncthreads();
  if (tid < 8) part[blockIdx.x * 8 + tid] = lh[0][tid] + lh[1][tid] + lh[2][tid] + lh[3][tid];
}

// ---------------- single-wave scan: counts/offs + per-chunk bases ----------
__global__ void k_scan(const int* __restrict__ part, int* __restrict__ base,
                       int* __restrict__ counts, int* __restrict__ offs) {
  const int lane = threadIdx.x;  // 64 threads = one wave
  int run = 0;
#pragma unroll
  for (int e = 0; e < 8; ++e) {
    int v = (lane < 32) ? part[lane * 8 + e] : 0;
    int s = v;
#pragma unroll
    for (int off = 1; off < 64; off <<= 1) {
      int u = __shfl_up(s, off);
      if (lane >= off) s += u;
    }
    int tot = __shfl(s, 31);
    if (lane < 32) base[lane * 8 + e] = run + (s - v);
    if (lane == 0) { counts[e] = tot; offs[e] = run; }
    run += tot;
  }
}

// ---------------- scatter with per-block LDS cursors (no global atomics) ---
__global__ __launch_bounds__(256) void k_scatter(const int* __restrict__ e0a,
                                                 const int* __restrict__ e1a,
                                                 const float* __restrict__ w0a,
                                                 const float* __restrict__ w1a,
                                                 const int* __restrict__ base,
                                                 int* __restrict__ entries,
                                                 float* __restrict__ ew,
                                                 int* __restrict__ slot0,
                                                 int* __restrict__ slot1) {
  __shared__ int cur[8];
  const int tid = threadIdx.x;
  if (tid < 8) cur[tid] = base[blockIdx.x * 8 + tid];
  __syncthreads();
  const int t = blockIdx.x * 256 + tid;
  int e0 = e0a[t];
  int i0 = atomicAdd(&cur[e0], 1);
  entries[i0] = t; ew[i0] = w0a[t]; slot0[t] = i0;
  int e1 = e1a[t];
  int i1 = atomicAdd(&cur[e1], 1);
  entries[i1] = t; ew[i1] = w1a[t]; slot1[t] = i1;
}

// ---------------- expert GEMM 1: h = relu(x[gather] @ w1[e]^T) -------------
__global__ __launch_bounds__(256) void k_ffn1(const bf16* __restrict__ X,
                                              const bf16* __restrict__ w1b,
                                              const float* __restrict__ b1,
                                              const int* __restrict__ entries,
                                              const int* __restrict__ counts,
                                              const int* __restrict__ offs,
                                              bf16* __restrict__ hbuf) {
  const int e = blockIdx.z;
  const int ne = counts[e];
  if ((int)(blockIdx.x * 128) >= ne) return;
  const int base = offs[e];
  const int w = threadIdx.x >> 6, lane = threadIdx.x & 63;
  const int mbase = blockIdx.x * 128 + (w >> 1) * 64;
  const int nbase = blockIdx.y * 128 + (w & 1) * 64;
  const int r = lane & 15, g4 = lane >> 4;
  int arow[4];
#pragma unroll
  for (int i = 0; i < 4; ++i) {
    int mm = mbase + i * 16 + r;
    if (mm > ne - 1) mm = ne - 1;
    arow[i] = entries[base + mm];
  }
  fx4 acc[4][4] = {};
  gemm_core<8>(X, arow, 256, w1b + (size_t)e * 262144, nbase, 256, lane, acc);
  const float* be = b1 + e * 1024;
#pragma unroll
  for (int i = 0; i < 4; ++i)
#pragma unroll
    for (int j = 0; j < 4; ++j)
#pragma unroll
      for (int jj = 0; jj < 4; ++jj) {
        int mm = mbase + i * 16 + g4 * 4 + jj;
        if (mm < ne) {
          int nn = nbase + j * 16 + r;
          float v = fmaxf(acc[i][j][jj] + be[nn], 0.f);
          hbuf[(size_t)(base + mm) * 1024 + nn] = f2b(v);
        }
      }
}

// ---------------- expert GEMM 2: ybuf[slot] = w*(h @ w2[e]^T + b2) ---------
__global__ __launch_bounds__(256) void k_ffn2(const bf16* __restrict__ hbuf,
                                              const bf16* __restrict__ w2b,
                                              const float* __restrict__ b2,
                                              const float* __restrict__ ew,
                                              const int* __restrict__ counts,
                                              const int* __restrict__ offs,
                                              float* __restrict__ ybuf) {
  const int e = blockIdx.z;
  const int ne = counts[e];
  if ((int)(blockIdx.x * 128) >= ne) return;
  const int base = offs[e];
  const int w = threadIdx.x >> 6, lane = threadIdx.x & 63;
  const int mbase = blockIdx.x * 128 + (w >> 1) * 64;
  const int nbase = blockIdx.y * 128 + (w & 1) * 64;
  const int r = lane & 15, g4 = lane >> 4;
  int arow[4];
#pragma unroll
  for (int i = 0; i < 4; ++i) {
    int mm = mbase + i * 16 + r;
    if (mm > ne - 1) mm = ne - 1;
    arow[i] = base + mm;
  }
  fx4 acc[4][4] = {};
  gemm_core<32>(hbuf, arow, 1024, w2b + (size_t)e * 262144, nbase, 1024, lane, acc);
  const float* be = b2 + e * 256;
#pragma unroll
  for (int i = 0; i < 4; ++i)
#pragma unroll
    for (int j = 0; j < 4; ++j)
#pragma unroll
      for (int jj = 0; jj < 4; ++jj) {
        int mm = mbase + i * 16 + g4 * 4 + jj;
        if (mm < ne) {
          int nn = nbase + j * 16 + r;
          int idx = base + mm;
          ybuf[(size_t)idx * 256 + nn] = (acc[i][j][jj] + be[nn]) * ew[idx];
        }
      }
}

// ---------------- final: out = tgt2 + ybuf[slot0] + ybuf[slot1] ------------
__global__ __launch_bounds__(256) void k_final(const float* __restrict__ tgt2,
                                               const float* __restrict__ ybuf,
                                               const int* __restrict__ slot0,
                                               const int* __restrict__ slot1,
                                               float* __restrict__ o) {
  const int w = threadIdx.x >> 6, lane = threadIdx.x & 63;
  const int t = blockIdx.x * 4 + w;
  float4 a = reinterpret_cast<const float4*>(tgt2 + (size_t)t * 256)[lane];
  float4 y0 = reinterpret_cast<const float4*>(ybuf + (size_t)slot0[t] * 256)[lane];
  float4 y1 = reinterpret_cast<const float4*>(ybuf + (size_t)slot1[t] * 256)[lane];
  float4 z;
  z.x = a.x + y0.x + y1.x;
  z.y = a.y + y0.y + y1.y;
  z.z = a.z + y0.z + y1.z;
  z.w = a.w + y0.w + y1.w;
  reinterpret_cast<float4*>(o + (size_t)t * 256)[lane] = z;
}

extern "C" void kernel_launch(void* const* d_in, const int* in_sizes, int n_in,
                              void* d_out, int out_size, void* d_ws, size_t ws_size,
                              hipStream_t stream) {
  const float* in_out   = (const float*)d_in[0];
  const float* in_mem   = (const float*)d_in[1];
  const float* in_embed = (const float*)d_in[2];
  const float* sa_wi = (const float*)d_in[3];
  const float* sa_bi = (const float*)d_in[4];
  const float* sa_wo = (const float*)d_in[5];
  const float* sa_bo = (const float*)d_in[6];
  const float* ca_wi = (const float*)d_in[7];
  const float* ca_bi = (const float*)d_in[8];
  const float* ca_wo = (const float*)d_in[9];
  const float* ca_bo = (const float*)d_in[10];
  const float* n1g = (const float*)d_in[11];
  const float* n1b = (const float*)d_in[12];
  const float* n2g = (const float*)d_in[13];
  const float* n2b = (const float*)d_in[14];
  const float* gw = (const float*)d_in[15];
  const float* gb = (const float*)d_in[16];
  const float* w1 = (const float*)d_in[17];
  const float* b1 = (const float*)d_in[18];
  const float* w2 = (const float*)d_in[19];
  const float* b2 = (const float*)d_in[20];
  (void)in_sizes; (void)n_in; (void)out_size; (void)ws_size;

  char* p = (char*)d_ws;
  auto alloc = [&](size_t bytes) -> char* {
    char* q = p;
    p += (bytes + 511) & ~(size_t)511;
    return q;
  };
  // weights (split)
  bf16* sa_wi_h = (bf16*)alloc(196608 * 2); bf16* sa_wi_l = (bf16*)alloc(196608 * 2);
  bf16* ca_wi_h = (bf16*)alloc(196608 * 2); bf16* ca_wi_l = (bf16*)alloc(196608 * 2);
  bf16* sa_wo_h = (bf16*)alloc(65536 * 2);  bf16* sa_wo_l = (bf16*)alloc(65536 * 2);
  bf16* ca_wo_h = (bf16*)alloc(65536 * 2);  bf16* ca_wo_l = (bf16*)alloc(65536 * 2);
  bf16* w1_b    = (bf16*)alloc(2097152 * 2);
  bf16* w2_b    = (bf16*)alloc(2097152 * 2);
  // activations (split)
  bf16* embed_h = (bf16*)alloc(262144 * 2); bf16* embed_l = (bf16*)alloc(262144 * 2);
  bf16* mem_h   = (bf16*)alloc(2097152 * 2); bf16* mem_l  = (bf16*)alloc(2097152 * 2);
  bf16* out_h   = (bf16*)alloc(2097152 * 2); bf16* out_l  = (bf16*)alloc(2097152 * 2);
  bf16* q_sa_h  = (bf16*)alloc(262144 * 2);  bf16* q_sa_l = (bf16*)alloc(262144 * 2);
  bf16* k_h     = (bf16*)alloc(2097152 * 2); bf16* k_l    = (bf16*)alloc(2097152 * 2);
  bf16* v_h     = (bf16*)alloc(2097152 * 2); bf16* v_l    = (bf16*)alloc(2097152 * 2);
  bf16* attn_h  = (bf16*)alloc(2097152 * 2); bf16* attn_l = (bf16*)alloc(2097152 * 2);
  bf16* q_ca_h  = (bf16*)alloc(2097152 * 2); bf16* q_ca_l = (bf16*)alloc(2097152 * 2);
  float* y      = (float*)alloc(2097152 * 4);
  float* tgt1_f = (float*)alloc(2097152 * 4);
  bf16* tgt1_h  = (bf16*)alloc(2097152 * 2); bf16* tgt1_l = (bf16*)alloc(2097152 * 2);
  float* tgt2_f = (float*)alloc(2097152 * 4);
  bf16* tgt2_h  = (bf16*)alloc(2097152 * 2); bf16* tgt2_l = (bf16*)alloc(2097152 * 2);
  bf16* hbuf    = (bf16*)alloc((size_t)16384 * 1024 * 2);
  int* e0a      = (int*)alloc(8192 * 4);
  int* e1a      = (int*)alloc(8192 * 4);
  float* w0a    = (float*)alloc(8192 * 4);
  float* w1a    = (float*)alloc(8192 * 4);
  int* entries  = (int*)alloc(16384 * 4);
  float* ewt    = (float*)alloc(16384 * 4);
  int* slot0    = (int*)alloc(8192 * 4);
  int* slot1    = (int*)alloc(8192 * 4);
  int* part     = (int*)alloc(32 * 8 * 4);
  int* basep    = (int*)alloc(32 * 8 * 4);
  int* ctrl     = (int*)alloc(64);
  int* counts = ctrl;
  int* offs = ctrl + 8;
  // ybuf (16384 x 256 fp32 = 16.78 MB) aliases attn_h+attn_l (dead after
  // the CA out-projection; exactly 2 x 4,194,304 contiguous bytes).
  float* ybuf = (float*)attn_h;

  // fp32 -> bf16 hi/lo conversions
  CvtS cs{};
  cs.s[0] = sa_wi;    cs.dh[0] = sa_wi_h; cs.dl[0] = sa_wi_l;
  cs.s[1] = ca_wi;    cs.dh[1] = ca_wi_h; cs.dl[1] = ca_wi_l;
  cs.s[2] = sa_wo;    cs.dh[2] = sa_wo_h; cs.dl[2] = sa_wo_l;
  cs.s[3] = ca_wo;    cs.dh[3] = ca_wo_h; cs.dl[3] = ca_wo_l;
  cs.s[4] = in_embed; cs.dh[4] = embed_h; cs.dl[4] = embed_l;
  cs.s[5] = in_mem;   cs.dh[5] = mem_h;   cs.dl[5] = mem_l;
  cs.s[6] = in_out;   cs.dh[6] = out_h;   cs.dl[6] = out_l;
  int cumS[8] = {0, 196608, 393216, 458752, 524288, 786432, 2883584, 4980736};
  for (int i = 0; i < 8; ++i) cs.cum[i] = cumS[i];
  k_cvt_split<<<4864, 256, 0, stream>>>(cs, 1245184);

  CvtP cp{};
  cp.s[0] = w1; cp.d[0] = w1_b;
  cp.s[1] = w2; cp.d[1] = w2_b;
  cp.cum[0] = 0; cp.cum[1] = 2097152; cp.cum[2] = 4194304;
  k_cvt<<<4096, 256, 0, stream>>>(cp, 1048576);

  // ---- stage 1: attention over `memory` ----
  k_qproj_s<<<dim3(8, 2), 256, 0, stream>>>(embed_h, embed_l, sa_wi_h, sa_wi_l,
                                            sa_bi, q_sa_h, q_sa_l, 0);
  k_kvproj_s<<<dim3(64, 4), 256, 0, stream>>>(mem_h, mem_l, sa_wi_h + 65536,
                                              sa_wi_l + 65536, sa_bi + 256,
                                              k_h, k_l, v_h, v_l);
  k_attn_s<<<dim3(32, 64), 256, 0, stream>>>(q_sa_h, q_sa_l, k_h, k_l, v_h, v_l,
                                             attn_h, attn_l, 0);
  k_oproj_s<<<dim3(64, 2), 256, 0, stream>>>(attn_h, attn_l, sa_wo_h, sa_wo_l,
                                             sa_bo, in_embed, 1, y);
  k_ln<<<2048, 256, 0, stream>>>(y, n1g, n1b, tgt1_f, tgt1_h, tgt1_l);

  // ---- stage 2: attention over `out` ----
  k_qproj_s<<<dim3(64, 2), 256, 0, stream>>>(tgt1_h, tgt1_l, ca_wi_h, ca_wi_l,
                                             ca_bi, q_ca_h, q_ca_l, 1);
  k_kvproj_s<<<dim3(64, 4), 256, 0, stream>>>(out_h, out_l, ca_wi_h + 65536,
                                              ca_wi_l + 65536, ca_bi + 256,
                                              k_h, k_l, v_h, v_l);
  k_attn_s<<<dim3(32, 64), 256, 0, stream>>>(q_ca_h, q_ca_l, k_h, k_l, v_h, v_l,
                                             attn_h, attn_l, 1);
  k_oproj_s<<<dim3(64, 2), 256, 0, stream>>>(attn_h, attn_l, ca_wo_h, ca_wo_l,
                                             ca_bo, tgt1_f, 0, y);
  k_ln<<<2048, 256, 0, stream>>>(y, n2g, n2b, tgt2_f, tgt2_h, tgt2_l);

  // ---- stage 3: MoE FFN (atomic-free routing) ----
  k_gate<<<2048, 256, 0, stream>>>(tgt2_f, gw, gb, e0a, e1a, w0a, w1a);
  k_hist<<<32, 256, 0, stream>>>(e0a, e1a, part);
  k_scan<<<1, 64, 0, stream>>>(part, basep, counts, offs);
  k_scatter<<<32, 256, 0, stream>>>(e0a, e1a, w0a, w1a, basep, entries, ewt, slot0, slot1);
  k_ffn1<<<dim3(128, 8, 8), 256, 0, stream>>>(tgt2_h, w1_b, b1, entries, counts, offs, hbuf);
  k_ffn2<<<dim3(128, 2, 8), 256, 0, stream>>>(hbuf, w2_b, b2, ewt, counts, offs, ybuf);
  k_final<<<2048, 256, 0, stream>>>(tgt2_f, ybuf, slot0, slot1, (float*)d_out);
}

// Round 8
// 565.342 us; speedup vs baseline: 1.4428x; 1.4428x over previous
//
#include <hip/hip_runtime.h>
#include <hip/hip_bf16.h>

// ShareDeLayer: 2x cross-attention + 2x LayerNorm + top2-of-8 MoE FFN.
// Q=1024, S=1024, B=8, D=256, H=8, hd=32, FF=1024, E=8, K=2.
// Pre-gate chain: bf16x2-split MFMA (3 products) ~= fp32 fidelity so the
// discrete top-2 routing matches the numpy fp32 reference.
// Round 8: attention — keep swapped-QK^T register-only loop (r7, verified),
// fix its two regressions: (1) V stored FRAGMENT-MAJOR so the PV B-operand
// is one coalesced 16B/lane load per 16-s block; (2) 6 independent PV
// accumulators (chain 96 -> 32) + explicit 2-stage K/V prefetch pipeline.

#define DEV static __device__ __forceinline__

typedef __hip_bfloat16 bf16;
typedef __bf16 b8 __attribute__((ext_vector_type(8)));
typedef __bf16 b4 __attribute__((ext_vector_type(4)));
typedef short s4 __attribute__((ext_vector_type(4)));
typedef float fx4 __attribute__((ext_vector_type(4)));

DEV bf16 f2b(float f) { return __float2bfloat16(f); }
DEV float b2f(bf16 h) { return __bfloat162float(h); }

DEV fx4 mfma16(b4 a, b4 b, fx4 c) {
#if __has_builtin(__builtin_amdgcn_mfma_f32_16x16x16_bf16)
  return __builtin_amdgcn_mfma_f32_16x16x16_bf16(a, b, c, 0, 0, 0);
#elif __has_builtin(__builtin_amdgcn_mfma_f32_16x16x16bf16_1k)
  s4 as = __builtin_bit_cast(s4, a);
  s4 bs = __builtin_bit_cast(s4, b);
  return __builtin_amdgcn_mfma_f32_16x16x16bf16_1k(as, bs, c, 0, 0, 0);
#else
  asm("v_mfma_f32_16x16x16_bf16 %0, %1, %2, %0" : "+v"(c) : "v"(a), "v"(b));
  return c;
#endif
}

// ---------------- single-precision MFMA core (MoE experts) -----------------
template <int KSTEPS>
DEV void gemm_core(const bf16* __restrict__ A, const int* arow, int lda,
                   const bf16* __restrict__ W, int nbase, int ldb, int lane,
                   fx4 acc[4][4]) {
  const int r = lane & 15, ko = (lane >> 4) * 8;
  const b8* ap[4];
  const b8* bp[4];
#pragma unroll
  for (int i = 0; i < 4; ++i) {
    ap[i] = reinterpret_cast<const b8*>(A + (size_t)arow[i] * lda + ko);
    bp[i] = reinterpret_cast<const b8*>(W + (size_t)(nbase + i * 16 + r) * ldb + ko);
  }
#pragma unroll 4
  for (int ks = 0; ks < KSTEPS; ++ks) {
    b8 a[4], b[4];
#pragma unroll
    for (int i = 0; i < 4; ++i) { a[i] = ap[i][ks * 4]; b[i] = bp[i][ks * 4]; }
#pragma unroll
    for (int i = 0; i < 4; ++i)
#pragma unroll
      for (int j = 0; j < 4; ++j)
        acc[i][j] = __builtin_amdgcn_mfma_f32_16x16x32_bf16(a[i], b[j], acc[i][j], 0, 0, 0);
  }
}

// ---------------- split (hi+lo) MFMA core: ~fp32 via 3 products ------------
template <int KSTEPS>
DEV void gemm3(const bf16* __restrict__ Ah, const bf16* __restrict__ Al,
               const int* arow, int lda,
               const bf16* __restrict__ Wh, const bf16* __restrict__ Wl,
               int nbase, int ldb, int lane, fx4 acc[4][4]) {
  const int r = lane & 15, ko = (lane >> 4) * 8;
  const b8 *aph[4], *apl[4], *bph[4], *bpl[4];
#pragma unroll
  for (int i = 0; i < 4; ++i) {
    size_t ao = (size_t)arow[i] * lda + ko;
    size_t bo = (size_t)(nbase + i * 16 + r) * ldb + ko;
    aph[i] = reinterpret_cast<const b8*>(Ah + ao);
    apl[i] = reinterpret_cast<const b8*>(Al + ao);
    bph[i] = reinterpret_cast<const b8*>(Wh + bo);
    bpl[i] = reinterpret_cast<const b8*>(Wl + bo);
  }
#pragma unroll 2
  for (int ks = 0; ks < KSTEPS; ++ks) {
    b8 ah[4], al[4], bh[4], bl[4];
#pragma unroll
    for (int i = 0; i < 4; ++i) {
      ah[i] = aph[i][ks * 4]; al[i] = apl[i][ks * 4];
      bh[i] = bph[i][ks * 4]; bl[i] = bpl[i][ks * 4];
    }
#pragma unroll
    for (int i = 0; i < 4; ++i)
#pragma unroll
      for (int j = 0; j < 4; ++j) {
        acc[i][j] = __builtin_amdgcn_mfma_f32_16x16x32_bf16(ah[i], bh[j], acc[i][j], 0, 0, 0);
        acc[i][j] = __builtin_amdgcn_mfma_f32_16x16x32_bf16(ah[i], bl[j], acc[i][j], 0, 0, 0);
        acc[i][j] = __builtin_amdgcn_mfma_f32_16x16x32_bf16(al[i], bh[j], acc[i][j], 0, 0, 0);
      }
  }
}

// ---------------- fp32 -> bf16 hi/lo split converter -----------------------
struct CvtS {
  const float* s[7];
  bf16* dh[7];
  bf16* dl[7];
  int cum[8];
};

__global__ __launch_bounds__(256) void k_cvt_split(CvtS c, int total4) {
  int i = blockIdx.x * 256 + threadIdx.x;
  if (i >= total4) return;
  int idx = i * 4;
#pragma unroll
  for (int seg = 0; seg < 7; ++seg) {
    if (idx < c.cum[seg + 1]) {
      int l = idx - c.cum[seg];
      float4 v = *reinterpret_cast<const float4*>(c.s[seg] + l);
      bf16* dh = c.dh[seg] + l;
      bf16* dl = c.dl[seg] + l;
      float a[4] = {v.x, v.y, v.z, v.w};
#pragma unroll
      for (int t = 0; t < 4; ++t) {
        bf16 h = f2b(a[t]);
        dh[t] = h;
        dl[t] = f2b(a[t] - b2f(h));
      }
      return;
    }
  }
}

struct CvtP {
  const float* s[2];
  bf16* d[2];
  int cum[3];
};

__global__ __launch_bounds__(256) void k_cvt(CvtP c, int total4) {
  int i = blockIdx.x * 256 + threadIdx.x;
  if (i >= total4) return;
  int idx = i * 4;
#pragma unroll
  for (int seg = 0; seg < 2; ++seg) {
    if (idx < c.cum[seg + 1]) {
      int l = idx - c.cum[seg];
      float4 v = *reinterpret_cast<const float4*>(c.s[seg] + l);
      bf16* dp = c.d[seg] + l;
      dp[0] = f2b(v.x); dp[1] = f2b(v.y); dp[2] = f2b(v.z); dp[3] = f2b(v.w);
      return;
    }
  }
}

// ---------------- Q projection (split, fused 1/sqrt(32)) -------------------
__global__ __launch_bounds__(256) void k_qproj_s(
    const bf16* __restrict__ Ah, const bf16* __restrict__ Al,
    const bf16* __restrict__ Wh, const bf16* __restrict__ Wl,
    const float* __restrict__ bias,
    bf16* __restrict__ qh, bf16* __restrict__ ql, int isCA) {
  const int w = threadIdx.x >> 6, lane = threadIdx.x & 63;
  const int mbase = blockIdx.x * 128 + (w >> 1) * 64;
  const int nbase = blockIdx.y * 128 + (w & 1) * 64;
  const int r = lane & 15, g4 = lane >> 4;
  int arow[4];
#pragma unroll
  for (int i = 0; i < 4; ++i) arow[i] = mbase + i * 16 + r;
  fx4 acc[4][4] = {};
  gemm3<8>(Ah, Al, arow, 256, Wh, Wl, nbase, 256, lane, acc);
#pragma unroll
  for (int i = 0; i < 4; ++i)
#pragma unroll
    for (int j = 0; j < 4; ++j)
#pragma unroll
      for (int jj = 0; jj < 4; ++jj) {
        int mm = mbase + i * 16 + g4 * 4 + jj;
        int nn = nbase + j * 16 + r;
        float v = (acc[i][j][jj] + bias[nn]) * 0.17677669529663687f;
        int h = nn >> 5, d = nn & 31;
        size_t o;
        if (isCA) o = (((size_t)((mm & 7) * 8 + h)) * 1024 + (mm >> 3)) * 32 + d;
        else      o = ((size_t)h * 1024 + mm) * 32 + d;
        bf16 hv = f2b(v);
        qh[o] = hv;
        ql[o] = f2b(v - b2f(hv));
      }
}

// ---------------- K/V projection (split; N=512 [wk;wv]) --------------------
// K: [bh][s][32] row-major. V: FRAGMENT-MAJOR VF[bh][sb][lane][8]:
// lane l = g4v*16 + (d&15), elems = {db=0: j=0..3, db=1: j=0..3}, where
// sb = s>>4, g4v = (s&15)>>2, j = s&3, db = d>>4. One coalesced b8 per
// (bh, sb, plane) in the attention PV loop.
__global__ __launch_bounds__(256) void k_kvproj_s(
    const bf16* __restrict__ Ah, const bf16* __restrict__ Al,
    const bf16* __restrict__ Wh, const bf16* __restrict__ Wl,
    const float* __restrict__ bias,
    bf16* __restrict__ kh, bf16* __restrict__ kl,
    bf16* __restrict__ vh, bf16* __restrict__ vl) {
  const int w = threadIdx.x >> 6, lane = threadIdx.x & 63;
  const int mbase = blockIdx.x * 128 + (w >> 1) * 64;
  const int nbase = blockIdx.y * 128 + (w & 1) * 64;
  const int r = lane & 15, g4 = lane >> 4;
  int arow[4];
#pragma unroll
  for (int i = 0; i < 4; ++i) arow[i] = mbase + i * 16 + r;
  fx4 acc[4][4] = {};
  gemm3<8>(Ah, Al, arow, 256, Wh, Wl, nbase, 256, lane, acc);
#pragma unroll
  for (int i = 0; i < 4; ++i)
#pragma unroll
    for (int j = 0; j < 4; ++j)
#pragma unroll
      for (int jj = 0; jj < 4; ++jj) {
        int mm = mbase + i * 16 + g4 * 4 + jj;
        int nn = nbase + j * 16 + r;
        float v = acc[i][j][jj] + bias[nn];
        int s = mm >> 3, bb = mm & 7;
        int hh = (nn & 255) >> 5, d = nn & 31;
        bf16 hv = f2b(v);
        bf16 lv = f2b(v - b2f(hv));
        if (nn < 256) {
          size_t o = (((size_t)(bb * 8 + hh)) * 1024 + s) * 32 + d;
          kh[o] = hv; kl[o] = lv;
        } else {
          int sb = s >> 4, sl = s & 15;
          int g4v = sl >> 2, jv = sl & 3;
          int db = d >> 4, rv = d & 15;
          size_t o = ((((size_t)(bb * 8 + hh)) * 64 + sb) * 64 +
                      (g4v * 16 + rv)) * 8 + db * 4 + jv;
          vh[o] = hv; vl[o] = lv;
        }
      }
}

// ---------------- flash attention, split precision, register-only loop -----
// grid (32, 64); flat id n = c + 8*(xt + 32*a) pins bh = 8a+c to XCD c.
// Block: 32 q rows; 4 waves = 2 q-tiles x 2 s-halves. Swapped QK^T
// (mfma(K,Q)): C col = q (lane&15), row = s_local — equals the K=16 MFMA
// A-fragment layout, so exp(P) feeds PV directly in registers. V is
// fragment-major (one coalesced b8/lane per plane per 16-s block).
// 6 independent PV accumulators; 2-stage K/V prefetch pipeline.
__global__ __launch_bounds__(256, 4) void k_attn_s(
    const bf16* __restrict__ qth, const bf16* __restrict__ qtl,
    const bf16* __restrict__ kth, const bf16* __restrict__ ktl,
    const bf16* __restrict__ vth, const bf16* __restrict__ vtl,
    bf16* __restrict__ aoh, bf16* __restrict__ aol, int caFlag) {
  __shared__ float Cb[4][64][12];
  const int w = threadIdx.x >> 6, lane = threadIdx.x & 63;
  const int n = blockIdx.y * 32 + blockIdx.x;
  const int cx = n & 7, rem = n >> 3;
  const int xt = rem & 31, a = rem >> 5;
  const int bh = a * 8 + cx;
  const int b = bh >> 3, h = bh & 7;
  const int q0 = xt * 32 + (w >> 1) * 16;
  const int sb0 = (w & 1) * 32;  // s-half start, in 16-s blocks
  const int r = lane & 15, g4 = lane >> 4, ko8 = g4 * 8;
  const size_t qoff = (size_t)(caFlag ? bh : h) * 32768;
  const size_t koff = (size_t)bh * 32768;
  const size_t voff = (size_t)bh * 32768;
  const b8 qfh = *reinterpret_cast<const b8*>(qth + qoff + (size_t)(q0 + r) * 32 + ko8);
  const b8 qfl = *reinterpret_cast<const b8*>(qtl + qoff + (size_t)(q0 + r) * 32 + ko8);
  const fx4 zz = {};
  fx4 ahh0 = {}, ahl0 = {}, alh0 = {}, ahh1 = {}, ahl1 = {}, alh1 = {};
  float ls0 = 0.f, ls1 = 0.f, ls2 = 0.f, ls3 = 0.f;

  b8 kA_h, kA_l, vA_h, vA_l, kB_h, kB_l, vB_h, vB_l;
  auto loadA = [&](int sb) {
    size_t ka = koff + (size_t)(sb * 16 + r) * 32 + ko8;
    size_t va = voff + ((size_t)sb * 64 + lane) * 8;
    kA_h = *reinterpret_cast<const b8*>(kth + ka);
    kA_l = *reinterpret_cast<const b8*>(ktl + ka);
    vA_h = *reinterpret_cast<const b8*>(vth + va);
    vA_l = *reinterpret_cast<const b8*>(vtl + va);
  };
  auto loadB = [&](int sb) {
    size_t ka = koff + (size_t)(sb * 16 + r) * 32 + ko8;
    size_t va = voff + ((size_t)sb * 64 + lane) * 8;
    kB_h = *reinterpret_cast<const b8*>(kth + ka);
    kB_l = *reinterpret_cast<const b8*>(ktl + ka);
    vB_h = *reinterpret_cast<const b8*>(vth + va);
    vB_l = *reinterpret_cast<const b8*>(vtl + va);
  };
  auto compute = [&](b8 kfh, b8 kfl, b8 vh8, b8 vl8) {
    fx4 t = __builtin_amdgcn_mfma_f32_16x16x32_bf16(kfh, qfl, zz, 0, 0, 0);
    t = __builtin_amdgcn_mfma_f32_16x16x32_bf16(kfl, qfh, t, 0, 0, 0);
    fx4 sf = __builtin_amdgcn_mfma_f32_16x16x32_bf16(kfh, qfh, t, 0, 0, 0);
    float p0 = __expf(sf[0]), p1 = __expf(sf[1]);
    float p2 = __expf(sf[2]), p3 = __expf(sf[3]);
    ls0 += p0; ls1 += p1; ls2 += p2; ls3 += p3;
    b4 ph, pl;
    ph[0] = (__bf16)p0; pl[0] = (__bf16)(p0 - (float)ph[0]);
    ph[1] = (__bf16)p1; pl[1] = (__bf16)(p1 - (float)ph[1]);
    ph[2] = (__bf16)p2; pl[2] = (__bf16)(p2 - (float)ph[2]);
    ph[3] = (__bf16)p3; pl[3] = (__bf16)(p3 - (float)ph[3]);
    b4 v0h = __builtin_shufflevector(vh8, vh8, 0, 1, 2, 3);
    b4 v1h = __builtin_shufflevector(vh8, vh8, 4, 5, 6, 7);
    b4 v0l = __builtin_shufflevector(vl8, vl8, 0, 1, 2, 3);
    b4 v1l = __builtin_shufflevector(vl8, vl8, 4, 5, 6, 7);
    ahh0 = mfma16(ph, v0h, ahh0);
    ahl0 = mfma16(ph, v0l, ahl0);
    alh0 = mfma16(pl, v0h, alh0);
    ahh1 = mfma16(ph, v1h, ahh1);
    ahl1 = mfma16(ph, v1l, ahl1);
    alh1 = mfma16(pl, v1h, alh1);
  };

  loadA(sb0);
#pragma unroll
  for (int i = 0; i < 16; ++i) {
    loadB(sb0 + 2 * i + 1);
    compute(kA_h, kA_l, vA_h, vA_l);
    if (i < 15) loadA(sb0 + 2 * i + 2);
    compute(kB_h, kB_l, vB_h, vB_l);
  }

  fx4 o0, o1;
#pragma unroll
  for (int j = 0; j < 4; ++j) {
    o0[j] = ahh0[j] + ahl0[j] + alh0[j];
    o1[j] = ahh1[j] + ahl1[j] + alh1[j];
  }
  float lsum = ls0 + ls1 + ls2 + ls3;
  // full row-sum for q=lane&15 over this s-half (sum the 4 g-groups)
  lsum += __shfl_xor(lsum, 16);
  lsum += __shfl_xor(lsum, 32);
  // ---- s-half combine ----
  __syncthreads();
  {
    float* cw = &Cb[w][lane][0];
    cw[0] = lsum;
#pragma unroll
    for (int j = 0; j < 4; ++j) { cw[1 + j] = o0[j]; cw[5 + j] = o1[j]; }
  }
  __syncthreads();
  if ((w & 1) == 0) {
    const float* cp = &Cb[w ^ 1][lane][0];
    float lt = lsum + cp[0];
#pragma unroll
    for (int j = 0; j < 4; ++j) {
      float lrow = __shfl(lt, 4 * g4 + j);  // lane whose q-col == this row
      float inv = 1.f / lrow;
      float a0 = (o0[j] + cp[1 + j]) * inv;
      float a1 = (o1[j] + cp[5 + j]) * inv;
      int q = q0 + 4 * g4 + j;
      size_t rowoff = ((size_t)q * 8 + b) * 256 + h * 32;
      bf16 h0 = f2b(a0), h1 = f2b(a1);
      aoh[rowoff + r] = h0;      aol[rowoff + r] = f2b(a0 - b2f(h0));
      aoh[rowoff + 16 + r] = h1; aol[rowoff + 16 + r] = f2b(a1 - b2f(h1));
    }
  }
}

// ---------------- out-proj (split) + bias + residual (fp32 out) ------------
__global__ __launch_bounds__(256) void k_oproj_s(
    const bf16* __restrict__ Ah, const bf16* __restrict__ Al,
    const bf16* __restrict__ Wh, const bf16* __restrict__ Wl,
    const float* __restrict__ bias, const float* __restrict__ res,
    int resBroadcast, float* __restrict__ yo) {
  const int w = threadIdx.x >> 6, lane = threadIdx.x & 63;
  const int mbase = blockIdx.x * 128 + (w >> 1) * 64;
  const int nbase = blockIdx.y * 128 + (w & 1) * 64;
  const int r = lane & 15, g4 = lane >> 4;
  int arow[4];
#pragma unroll
  for (int i = 0; i < 4; ++i) arow[i] = mbase + i * 16 + r;
  fx4 acc[4][4] = {};
  gemm3<8>(Ah, Al, arow, 256, Wh, Wl, nbase, 256, lane, acc);
#pragma unroll
  for (int i = 0; i < 4; ++i)
#pragma unroll
    for (int j = 0; j < 4; ++j)
#pragma unroll
      for (int jj = 0; jj < 4; ++jj) {
        int mm = mbase + i * 16 + g4 * 4 + jj;
        int nn = nbase + j * 16 + r;
        size_t roff = resBroadcast ? (size_t)(mm >> 3) * 256 : (size_t)mm * 256;
        yo[(size_t)mm * 256 + nn] = acc[i][j][jj] + bias[nn] + res[roff + nn];
      }
}

// ---------------- LayerNorm D=256; emits fp32 + bf16 hi/lo -----------------
__global__ __launch_bounds__(256) void k_ln(const float* __restrict__ y,
                                            const float* __restrict__ g,
                                            const float* __restrict__ bta,
                                            float* __restrict__ of,
                                            bf16* __restrict__ obh,
                                            bf16* __restrict__ obl) {
  const int row = blockIdx.x * 4 + (threadIdx.x >> 6);
  const int lane = threadIdx.x & 63;
  float4 x = reinterpret_cast<const float4*>(y + (size_t)row * 256)[lane];
  float s1 = x.x + x.y + x.z + x.w;
  float s2 = x.x * x.x + x.y * x.y + x.z * x.z + x.w * x.w;
#pragma unroll
  for (int m = 1; m < 64; m <<= 1) {
    s1 += __shfl_xor(s1, m);
    s2 += __shfl_xor(s2, m);
  }
  float mean = s1 * (1.0f / 256.0f);
  float var = s2 * (1.0f / 256.0f) - mean * mean;
  float rs = 1.0f / sqrtf(var + 1e-5f);
  float4 gv = reinterpret_cast<const float4*>(g)[lane];
  float4 bv = reinterpret_cast<const float4*>(bta)[lane];
  float o[4];
  o[0] = (x.x - mean) * rs * gv.x + bv.x;
  o[1] = (x.y - mean) * rs * gv.y + bv.y;
  o[2] = (x.z - mean) * rs * gv.z + bv.z;
  o[3] = (x.w - mean) * rs * gv.w + bv.w;
  float4 ov = {o[0], o[1], o[2], o[3]};
  reinterpret_cast<float4*>(of + (size_t)row * 256)[lane] = ov;
  bf16* dh = obh + (size_t)row * 256 + lane * 4;
  bf16* dl = obl + (size_t)row * 256 + lane * 4;
#pragma unroll
  for (int t = 0; t < 4; ++t) {
    bf16 hv = f2b(o[t]);
    dh[t] = hv;
    dl[t] = f2b(o[t] - b2f(hv));
  }
}

// ---------------- MoE gate: top2-of-8 (fp64 acc), NO atomics ---------------
__global__ __launch_bounds__(256) void k_gate(const float* __restrict__ x,
                                              const float* __restrict__ gw,
                                              const float* __restrict__ gb,
                                              int* __restrict__ e0a, int* __restrict__ e1a,
                                              float* __restrict__ w0a, float* __restrict__ w1a) {
  __shared__ float W[2048];
  const int tid = threadIdx.x;
  for (int i = tid; i < 2048; i += 256) W[i] = gw[i];
  __syncthreads();
  const int wv = tid >> 6, lane = tid & 63;
  const int t = blockIdx.x * 4 + wv;
  float4 v = reinterpret_cast<const float4*>(x + (size_t)t * 256)[lane];
  double pe[8];
#pragma unroll
  for (int e = 0; e < 8; ++e) {
    float4 wv4 = reinterpret_cast<const float4*>(&W[e * 256])[lane];
    pe[e] = (double)v.x * wv4.x + (double)v.y * wv4.y +
            (double)v.z * wv4.z + (double)v.w * wv4.w;
  }
#pragma unroll
  for (int e = 0; e < 8; ++e)
#pragma unroll
    for (int m = 1; m < 64; m <<= 1) pe[e] += __shfl_xor(pe[e], m);
  if (lane == 0) {
    float lg[8];
#pragma unroll
    for (int e = 0; e < 8; ++e) lg[e] = (float)(pe[e] + (double)gb[e]);
    int e0 = 0; float v0 = lg[0];
#pragma unroll
    for (int e = 1; e < 8; ++e) if (lg[e] > v0) { v0 = lg[e]; e0 = e; }
    int e1 = -1; float v1 = -1e30f;
#pragma unroll
    for (int e = 0; e < 8; ++e) {
      if (e == e0) continue;
      if (lg[e] > v1) { v1 = lg[e]; e1 = e; }
    }
    float z = __expf(v1 - v0);
    float inv = 1.f / (1.f + z);
    e0a[t] = e0; e1a[t] = e1; w0a[t] = inv; w1a[t] = z * inv;
  }
}

// ---------------- ballot histogram: part[chunk][8], chunk = 256 tokens -----
__global__ __launch_bounds__(256) void k_hist(const int* __restrict__ e0a,
                                              const int* __restrict__ e1a,
                                              int* __restrict__ part) {
  __shared__ int lh[4][8];
  const int tid = threadIdx.x, w = tid >> 6;
  const int t = blockIdx.x * 256 + tid;
  const int e0 = e0a[t], e1 = e1a[t];
  int cnt[8];
#pragma unroll
  for (int e = 0; e < 8; ++e) {
    unsigned long long m0 = __ballot(e0 == e);
    unsigned long long m1 = __ballot(e1 == e);
    cnt[e] = __popcll(m0) + __popcll(m1);
  }
  if ((tid & 63) == 0) {
#pragma unroll
    for (int e = 0; e < 8; ++e) lh[w][e] = cnt[e];
  }
  __syncthreads();
  if (tid < 8) part[blockIdx.x * 8 + tid] = lh[0][tid] + lh[1][tid] + lh[2][tid] + lh[3][tid];
}

// ---------------- single-wave scan: counts/offs + per-chunk bases ----------
__global__ void k_scan(const int* __restrict__ part, int* __restrict__ base,
                       int* __restrict__ counts, int* __restrict__ offs) {
  const int lane = threadIdx.x;  // 64 threads = one wave
  int run = 0;
#pragma unroll
  for (int e = 0; e < 8; ++e) {
    int v = (lane < 32) ? part[lane * 8 + e] : 0;
    int s = v;
#pragma unroll
    for (int off = 1; off < 64; off <<= 1) {
      int u = __shfl_up(s, off);
      if (lane >= off) s += u;
    }
    int tot = __shfl(s, 31);
    if (lane < 32) base[lane * 8 + e] = run + (s - v);
    if (lane == 0) { counts[e] = tot; offs[e] = run; }
    run += tot;
  }
}

// ---------------- scatter with per-block LDS cursors (no global atomics) ---
__global__ __launch_bounds__(256) void k_scatter(const int* __restrict__ e0a,
                                                 const int* __restrict__ e1a,
                                                 const float* __restrict__ w0a,
                                                 const float* __restrict__ w1a,
                                                 const int* __restrict__ base,
                                                 int* __restrict__ entries,
                                                 float* __restrict__ ew,
                                                 int* __restrict__ slot0,
                                                 int* __restrict__ slot1) {
  __shared__ int cur[8];
  const int tid = threadIdx.x;
  if (tid < 8) cur[tid] = base[blockIdx.x * 8 + tid];
  __syncthreads();
  const int t = blockIdx.x * 256 + tid;
  int e0 = e0a[t];
  int i0 = atomicAdd(&cur[e0], 1);
  entries[i0] = t; ew[i0] = w0a[t]; slot0[t] = i0;
  int e1 = e1a[t];
  int i1 = atomicAdd(&cur[e1], 1);
  entries[i1] = t; ew[i1] = w1a[t]; slot1[t] = i1;
}

// ---------------- expert GEMM 1: h = relu(x[gather] @ w1[e]^T) -------------
__global__ __launch_bounds__(256) void k_ffn1(const bf16* __restrict__ X,
                                              const bf16* __restrict__ w1b,
                                              const float* __restrict__ b1,
                                              const int* __restrict__ entries,
                                              const int* __restrict__ counts,
                                              const int* __restrict__ offs,
                                              bf16* __restrict__ hbuf) {
  const int e = blockIdx.z;
  const int ne = counts[e];
  if ((int)(blockIdx.x * 128) >= ne) return;
  const int base = offs[e];
  const int w = threadIdx.x >> 6, lane = threadIdx.x & 63;
  const int mbase = blockIdx.x * 128 + (w >> 1) * 64;
  const int nbase = blockIdx.y * 128 + (w & 1) * 64;
  const int r = lane & 15, g4 = lane >> 4;
  int arow[4];
#pragma unroll
  for (int i = 0; i < 4; ++i) {
    int mm = mbase + i * 16 + r;
    if (mm > ne - 1) mm = ne - 1;
    arow[i] = entries[base + mm];
  }
  fx4 acc[4][4] = {};
  gemm_core<8>(X, arow, 256, w1b + (size_t)e * 262144, nbase, 256, lane, acc);
  const float* be = b1 + e * 1024;
#pragma unroll
  for (int i = 0; i < 4; ++i)
#pragma unroll
    for (int j = 0; j < 4; ++j)
#pragma unroll
      for (int jj = 0; jj < 4; ++jj) {
        int mm = mbase + i * 16 + g4 * 4 + jj;
        if (mm < ne) {
          int nn = nbase + j * 16 + r;
          float v = fmaxf(acc[i][j][jj] + be[nn], 0.f);
          hbuf[(size_t)(base + mm) * 1024 + nn] = f2b(v);
        }
      }
}

// ---------------- expert GEMM 2: ybuf[slot] = w*(h @ w2[e]^T + b2) ---------
__global__ __launch_bounds__(256) void k_ffn2(const bf16* __restrict__ hbuf,
                                              const bf16* __restrict__ w2b,
                                              const float* __restrict__ b2,
                                              const float* __restrict__ ew,
                                              const int* __restrict__ counts,
                                              const int* __restrict__ offs,
                                              float* __restrict__ ybuf) {
  const int e = blockIdx.z;
  const int ne = counts[e];
  if ((int)(blockIdx.x * 128) >= ne) return;
  const int base = offs[e];
  const int w = threadIdx.x >> 6, lane = threadIdx.x & 63;
  const int mbase = blockIdx.x * 128 + (w >> 1) * 64;
  const int nbase = blockIdx.y * 128 + (w & 1) * 64;
  const int r = lane & 15, g4 = lane >> 4;
  int arow[4];
#pragma unroll
  for (int i = 0; i < 4; ++i) {
    int mm = mbase + i * 16 + r;
    if (mm > ne - 1) mm = ne - 1;
    arow[i] = base + mm;
  }
  fx4 acc[4][4] = {};
  gemm_core<32>(hbuf, arow, 1024, w2b + (size_t)e * 262144, nbase, 1024, lane, acc);
  const float* be = b2 + e * 256;
#pragma unroll
  for (int i = 0; i < 4; ++i)
#pragma unroll
    for (int j = 0; j < 4; ++j)
#pragma unroll
      for (int jj = 0; jj < 4; ++jj) {
        int mm = mbase + i * 16 + g4 * 4 + jj;
        if (mm < ne) {
          int nn = nbase + j * 16 + r;
          int idx = base + mm;
          ybuf[(size_t)idx * 256 + nn] = (acc[i][j][jj] + be[nn]) * ew[idx];
        }
      }
}

// ---------------- final: out = tgt2 + ybuf[slot0] + ybuf[slot1] ------------
__global__ __launch_bounds__(256) void k_final(const float* __restrict__ tgt2,
                                               const float* __restrict__ ybuf,
                                               const int* __restrict__ slot0,
                                               const int* __restrict__ slot1,
                                               float* __restrict__ o) {
  const int w = threadIdx.x >> 6, lane = threadIdx.x & 63;
  const int t = blockIdx.x * 4 + w;
  float4 a = reinterpret_cast<const float4*>(tgt2 + (size_t)t * 256)[lane];
  float4 y0 = reinterpret_cast<const float4*>(ybuf + (size_t)slot0[t] * 256)[lane];
  float4 y1 = reinterpret_cast<const float4*>(ybuf + (size_t)slot1[t] * 256)[lane];
  float4 z;
  z.x = a.x + y0.x + y1.x;
  z.y = a.y + y0.y + y1.y;
  z.z = a.z + y0.z + y1.z;
  z.w = a.w + y0.w + y1.w;
  reinterpret_cast<float4*>(o + (size_t)t * 256)[lane] = z;
}

extern "C" void kernel_launch(void* const* d_in, const int* in_sizes, int n_in,
                              void* d_out, int out_size, void* d_ws, size_t ws_size,
                              hipStream_t stream) {
  const float* in_out   = (const float*)d_in[0];
  const float* in_mem   = (const float*)d_in[1];
  const float* in_embed = (const float*)d_in[2];
  const float* sa_wi = (const float*)d_in[3];
  const float* sa_bi = (const float*)d_in[4];
  const float* sa_wo = (const float*)d_in[5];
  const float* sa_bo = (const float*)d_in[6];
  const float* ca_wi = (const float*)d_in[7];
  const float* ca_bi = (const float*)d_in[8];
  const float* ca_wo = (const float*)d_in[9];
  const float* ca_bo = (const float*)d_in[10];
  const float* n1g = (const float*)d_in[11];
  const float* n1b = (const float*)d_in[12];
  const float* n2g = (const float*)d_in[13];
  const float* n2b = (const float*)d_in[14];
  const float* gw = (const float*)d_in[15];
  const float* gb = (const float*)d_in[16];
  const float* w1 = (const float*)d_in[17];
  const float* b1 = (const float*)d_in[18];
  const float* w2 = (const float*)d_in[19];
  const float* b2 = (const float*)d_in[20];
  (void)in_sizes; (void)n_in; (void)out_size; (void)ws_size;

  char* p = (char*)d_ws;
  auto alloc = [&](size_t bytes) -> char* {
    char* q = p;
    p += (bytes + 511) & ~(size_t)511;
    return q;
  };
  // weights (split)
  bf16* sa_wi_h = (bf16*)alloc(196608 * 2); bf16* sa_wi_l = (bf16*)alloc(196608 * 2);
  bf16* ca_wi_h = (bf16*)alloc(196608 * 2); bf16* ca_wi_l = (bf16*)alloc(196608 * 2);
  bf16* sa_wo_h = (bf16*)alloc(65536 * 2);  bf16* sa_wo_l = (bf16*)alloc(65536 * 2);
  bf16* ca_wo_h = (bf16*)alloc(65536 * 2);  bf16* ca_wo_l = (bf16*)alloc(65536 * 2);
  bf16* w1_b    = (bf16*)alloc(2097152 * 2);
  bf16* w2_b    = (bf16*)alloc(2097152 * 2);
  // activations (split)
  bf16* embed_h = (bf16*)alloc(262144 * 2); bf16* embed_l = (bf16*)alloc(262144 * 2);
  bf16* mem_h   = (bf16*)alloc(2097152 * 2); bf16* mem_l  = (bf16*)alloc(2097152 * 2);
  bf16* out_h   = (bf16*)alloc(2097152 * 2); bf16* out_l  = (bf16*)alloc(2097152 * 2);
  bf16* q_sa_h  = (bf16*)alloc(262144 * 2);  bf16* q_sa_l = (bf16*)alloc(262144 * 2);
  bf16* k_h     = (bf16*)alloc(2097152 * 2); bf16* k_l    = (bf16*)alloc(2097152 * 2);
  bf16* v_h     = (bf16*)alloc(2097152 * 2); bf16* v_l    = (bf16*)alloc(2097152 * 2);
  bf16* attn_h  = (bf16*)alloc(2097152 * 2); bf16* attn_l = (bf16*)alloc(2097152 * 2);
  bf16* q_ca_h  = (bf16*)alloc(2097152 * 2); bf16* q_ca_l = (bf16*)alloc(2097152 * 2);
  float* y      = (float*)alloc(2097152 * 4);
  float* tgt1_f = (float*)alloc(2097152 * 4);
  bf16* tgt1_h  = (bf16*)alloc(2097152 * 2); bf16* tgt1_l = (bf16*)alloc(2097152 * 2);
  float* tgt2_f = (float*)alloc(2097152 * 4);
  bf16* tgt2_h  = (bf16*)alloc(2097152 * 2); bf16* tgt2_l = (bf16*)alloc(2097152 * 2);
  bf16* hbuf    = (bf16*)alloc((size_t)16384 * 1024 * 2);
  int* e0a      = (int*)alloc(8192 * 4);
  int* e1a      = (int*)alloc(8192 * 4);
  float* w0a    = (float*)alloc(8192 * 4);
  float* w1a    = (float*)alloc(8192 * 4);
  int* entries  = (int*)alloc(16384 * 4);
  float* ewt    = (float*)alloc(16384 * 4);
  int* slot0    = (int*)alloc(8192 * 4);
  int* slot1    = (int*)alloc(8192 * 4);
  int* part     = (int*)alloc(32 * 8 * 4);
  int* basep    = (int*)alloc(32 * 8 * 4);
  int* ctrl     = (int*)alloc(64);
  int* counts = ctrl;
  int* offs = ctrl + 8;
  // ybuf (16384 x 256 fp32 = 16.78 MB) aliases attn_h+attn_l (dead after
  // the CA out-projection; exactly 2 x 4,194,304 contiguous bytes).
  float* ybuf = (float*)attn_h;

  // fp32 -> bf16 hi/lo conversions
  CvtS cs{};
  cs.s[0] = sa_wi;    cs.dh[0] = sa_wi_h; cs.dl[0] = sa_wi_l;
  cs.s[1] = ca_wi;    cs.dh[1] = ca_wi_h; cs.dl[1] = ca_wi_l;
  cs.s[2] = sa_wo;    cs.dh[2] = sa_wo_h; cs.dl[2] = sa_wo_l;
  cs.s[3] = ca_wo;    cs.dh[3] = ca_wo_h; cs.dl[3] = ca_wo_l;
  cs.s[4] = in_embed; cs.dh[4] = embed_h; cs.dl[4] = embed_l;
  cs.s[5] = in_mem;   cs.dh[5] = mem_h;   cs.dl[5] = mem_l;
  cs.s[6] = in_out;   cs.dh[6] = out_h;   cs.dl[6] = out_l;
  int cumS[8] = {0, 196608, 393216, 458752, 524288, 786432, 2883584, 4980736};
  for (int i = 0; i < 8; ++i) cs.cum[i] = cumS[i];
  k_cvt_split<<<4864, 256, 0, stream>>>(cs, 1245184);

  CvtP cp{};
  cp.s[0] = w1; cp.d[0] = w1_b;
  cp.s[1] = w2; cp.d[1] = w2_b;
  cp.cum[0] = 0; cp.cum[1] = 2097152; cp.cum[2] = 4194304;
  k_cvt<<<4096, 256, 0, stream>>>(cp, 1048576);

  // ---- stage 1: attention over `memory` ----
  k_qproj_s<<<dim3(8, 2), 256, 0, stream>>>(embed_h, embed_l, sa_wi_h, sa_wi_l,
                                            sa_bi, q_sa_h, q_sa_l, 0);
  k_kvproj_s<<<dim3(64, 4), 256, 0, stream>>>(mem_h, mem_l, sa_wi_h + 65536,
                                              sa_wi_l + 65536, sa_bi + 256,
                                              k_h, k_l, v_h, v_l);
  k_attn_s<<<dim3(32, 64), 256, 0, stream>>>(q_sa_h, q_sa_l, k_h, k_l, v_h, v_l,
                                             attn_h, attn_l, 0);
  k_oproj_s<<<dim3(64, 2), 256, 0, stream>>>(attn_h, attn_l, sa_wo_h, sa_wo_l,
                                             sa_bo, in_embed, 1, y);
  k_ln<<<2048, 256, 0, stream>>>(y, n1g, n1b, tgt1_f, tgt1_h, tgt1_l);

  // ---- stage 2: attention over `out` ----
  k_qproj_s<<<dim3(64, 2), 256, 0, stream>>>(tgt1_h, tgt1_l, ca_wi_h, ca_wi_l,
                                             ca_bi, q_ca_h, q_ca_l, 1);
  k_kvproj_s<<<dim3(64, 4), 256, 0, stream>>>(out_h, out_l, ca_wi_h + 65536,
                                              ca_wi_l + 65536, ca_bi + 256,
                                              k_h, k_l, v_h, v_l);
  k_attn_s<<<dim3(32, 64), 256, 0, stream>>>(q_ca_h, q_ca_l, k_h, k_l, v_h, v_l,
                                             attn_h, attn_l, 1);
  k_oproj_s<<<dim3(64, 2), 256, 0, stream>>>(attn_h, attn_l, ca_wo_h, ca_wo_l,
                                             ca_bo, tgt1_f, 0, y);
  k_ln<<<2048, 256, 0, stream>>>(y, n2g, n2b, tgt2_f, tgt2_h, tgt2_l);

  // ---- stage 3: MoE FFN (atomic-free routing) ----
  k_gate<<<2048, 256, 0, stream>>>(tgt2_f, gw, gb, e0a, e1a, w0a, w1a);
  k_hist<<<32, 256, 0, stream>>>(e0a, e1a, part);
  k_scan<<<1, 64, 0, stream>>>(part, basep, counts, offs);
  k_scatter<<<32, 256, 0, stream>>>(e0a, e1a, w0a, w1a, basep, entries, ewt, slot0, slot1);
  k_ffn1<<<dim3(128, 8, 8), 256, 0, stream>>>(tgt2_h, w1_b, b1, entries, counts, offs, hbuf);
  k_ffn2<<<dim3(128, 2, 8), 256, 0, stream>>>(hbuf, w2_b, b2, ewt, counts, offs, ybuf);
  k_final<<<2048, 256, 0, stream>>>(tgt2_f, ybuf, slot0, slot1, (float*)d_out);
}